// Round 7
// baseline (8881.689 us; speedup 1.0000x reference)
//
#include <hip/hip_runtime.h>
#include <hip/hip_bf16.h>

#define BB 8
#define NN 2048
#define KK 20
#define BN (BB*NN)
#define MSPLIT 8   // total partial lists per n (gemm path: 4 z-chunks x 2 stripes)
#define RSQ 0.99999500003749969f   // 1/sqrt(1+1e-5)

// ---------------- workspace layout (float-slot units), 44.3 MiB total ----------------
constexpr size_t OFF_X1  = 0;                          // BN*64
constexpr size_t OFF_X2  = OFF_X1  + (size_t)BN*64;    // BN*64
constexpr size_t OFF_X3  = OFF_X2  + (size_t)BN*64;    // BN*128
constexpr size_t OFF_X4  = OFF_X3  + (size_t)BN*128;   // BN*256 (pv/pi alias here during knn)
constexpr size_t OFF_XX  = OFF_X4  + (size_t)BN*256;   // BN
constexpr size_t OFF_SC  = OFF_XX  + BN;               // scratch: q,bs (BN*128 of BN*160)
constexpr size_t OFF_ID  = OFF_SC  + (size_t)BN*160;   // int BN*20
constexpr size_t OFF_W5T = OFF_ID  + (size_t)BN*20;    // 512*512, [c][o]
constexpr size_t OFF_MX  = OFF_W5T + 512*512;          // uint B*512
constexpr size_t OFF_MN  = OFF_MX  + BB*512;
constexpr size_t WS_END  = OFF_MN  + BB*512;           // 11,624,448 floats

__device__ inline unsigned encf(float f){ unsigned u=__float_as_uint(f); return (u&0x80000000u)? ~u : (u|0x80000000u); }
__device__ inline float decf(unsigned e){ unsigned u=(e&0x80000000u)? (e&0x7fffffffu) : ~e; return __uint_as_float(u); }
__device__ inline float lrelu(float h){ return h>=0.f ? h : 0.2f*h; }

__device__ inline void ins20(float (&val)[KK], int (&ind)[KK], float cv, int ci){
  if (cv > val[KK-1]){
    #pragma unroll
    for(int j=0;j<KK;j++){
      if (cv > val[j]){ float tv=val[j]; int ti=ind[j]; val[j]=cv; ind[j]=ci; cv=tv; ci=ti; }
    }
  }
}

// ---------------- init ----------------
__global__ void transposeW5_k(const float* s, float* d){
  int i = blockIdx.x*256 + threadIdx.x;   // 262144
  int o = i>>9, c = i&511;
  d[c*512+o] = s[i];
}
__global__ void init_enc_k(unsigned* mx, unsigned* mn){
  int i = blockIdx.x*256 + threadIdx.x;   // 4096
  mx[i] = 0x007FFFFFu;   // enc(-inf)
  mn[i] = 0xFF800000u;   // enc(+inf)
}

// ---------------- KNN ----------------
template<int C>
__launch_bounds__(256) __global__ void sqnorm_k(const float* X, float* xx){
  int i = blockIdx.x*256 + threadIdx.x;   // BN
  const float* r = X + (size_t)i*C;
  float s = 0.f;
  #pragma unroll
  for(int c=0;c<C;c++) s = fmaf(r[c], r[c], s);
  xx[i] = s;
}

// old per-n kernel, kept only for C=3 (grid z = MSPLIT = 8 chunks)
template<int C, int MC>
__launch_bounds__(256) __global__ void knn_part2_k(const float* __restrict__ X, const float* __restrict__ xx,
                                                   float* __restrict__ pval, unsigned short* __restrict__ pidx){
  __shared__ float sm[MC*C];
  __shared__ float sxx[MC];
  const int b   = blockIdx.y;
  const int tid = threadIdx.x;
  const int n   = blockIdx.x*256 + tid;
  const float* Xb = X + (size_t)b*NN*C;
  float xn[C];
  #pragma unroll
  for(int c=0;c<C;c++) xn[c] = Xb[(size_t)n*C + c];
  const float xxn = xx[b*NN+n];
  const float* xxb = xx + b*NN;
  float val[KK]; int ind[KK];
  #pragma unroll
  for(int j=0;j<KK;j++){ val[j]=-INFINITY; ind[j]=0; }

  const int m0 = blockIdx.z*(NN/MSPLIT);
  for(int ms=m0; ms<m0+NN/MSPLIT; ms+=MC){
    __syncthreads();
    for(int i=tid; i<MC*C; i+=256) sm[i] = Xb[(size_t)ms*C + i];
    for(int i=tid; i<MC; i+=256) sxx[i] = xxb[ms+i];
    __syncthreads();
    for(int mg=0; mg<MC; mg+=4){
      float a0=0.f, a1=0.f, a2=0.f, a3=0.f;
      #pragma unroll
      for(int c=0;c<C;c++){
        float xc = xn[c];
        a0=fmaf(xc, sm[(size_t)(mg+0)*C+c], a0);
        a1=fmaf(xc, sm[(size_t)(mg+1)*C+c], a1);
        a2=fmaf(xc, sm[(size_t)(mg+2)*C+c], a2);
        a3=fmaf(xc, sm[(size_t)(mg+3)*C+c], a3);
      }
      float d0 = (2.f*a0 - xxn) - sxx[mg+0];
      float d1 = (2.f*a1 - xxn) - sxx[mg+1];
      float d2 = (2.f*a2 - xxn) - sxx[mg+2];
      float d3 = (2.f*a3 - xxn) - sxx[mg+3];
      float mx4 = fmaxf(fmaxf(d0,d1), fmaxf(d2,d3));
      if (mx4 > val[KK-1]){
        ins20(val, ind, d0, ms+mg+0);
        ins20(val, ind, d1, ms+mg+1);
        ins20(val, ind, d2, ms+mg+2);
        ins20(val, ind, d3, ms+mg+3);
      }
    }
  }
  float*          pv = pval + (((size_t)(b*NN+n))*MSPLIT + blockIdx.z)*KK;
  unsigned short* pi = pidx + (((size_t)(b*NN+n))*MSPLIT + blockIdx.z)*KK;
  #pragma unroll
  for(int j=0;j<KK;j++){ pv[j]=val[j]; pi[j]=(unsigned short)ind[j]; }
}

// GEMM-tiled KNN: block = 128n x 128m tile, thread = 8x8 micro-tile.
// Distances round-trip through LDS (two 64-col phases) for per-n selection.
// Accumulation: single fmaf chain, c ascending -> bit-identical to prior rounds.
template<int C>
__launch_bounds__(256,2) __global__ void knn_gemm_k(const float* __restrict__ X, const float* __restrict__ xx,
                                                    float* __restrict__ pval, unsigned short* __restrict__ pidx){
  constexpr int CCH = 16;
  constexpr int AST = 132;            // a/b tile row stride ([c][row], conflict-tuned)
  constexpr int DST = 68;             // d tile row stride
  __shared__ __align__(16) float a_sh[CCH*AST];
  __shared__ __align__(16) float b_sh[CCH*AST];
  __shared__ __align__(16) float d_sh[128*DST];
  __shared__ float sxx[128];

  const int tid = threadIdx.x;
  const int b   = blockIdx.y;
  const int ntile = blockIdx.x*128;
  const int mbase = blockIdx.z*(NN/4);
  // wave-local 8x8 (tn x tm) grid: frag reads are 8 distinct addrs -> 2-way (free)
  const int tn = (tid & 7) | ((tid >> 3) & 8);
  const int tm = ((tid >> 3) & 7) | ((tid >> 4) & 8);
  const int sn = tid >> 1, sh = tid & 1;

  const float* Xb  = X  + (size_t)b*NN*C;
  const float* xxb = xx + (size_t)b*NN;
  const float xxn_sel = xxb[ntile + sn];

  float val[KK]; int ind[KK];
  #pragma unroll
  for(int j=0;j<KK;j++){ val[j]=-INFINITY; ind[j]=0; }

  for(int mt=0; mt<4; ++mt){
    const int mtile = mbase + mt*128;
    __syncthreads();                       // prev tile's selection done
    if(tid < 128) sxx[tid] = xxb[mtile + tid];
    float acc[8][8];
    #pragma unroll
    for(int i=0;i<8;i++){
      #pragma unroll
      for(int j=0;j<8;j++) acc[i][j]=0.f;
    }
    for(int cc=0; cc<C; cc+=CCH){
      __syncthreads();                     // prev chunk's frag reads done
      #pragma unroll
      for(int s=0;s<2;s++){
        int i = tid + 256*s; int r = i>>2, q = i&3;
        float4 va = *(const float4*)&Xb[(size_t)(ntile + r)*C + cc + 4*q];
        a_sh[(4*q+0)*AST + r]=va.x; a_sh[(4*q+1)*AST + r]=va.y;
        a_sh[(4*q+2)*AST + r]=va.z; a_sh[(4*q+3)*AST + r]=va.w;
        float4 vb = *(const float4*)&Xb[(size_t)(mtile + r)*C + cc + 4*q];
        b_sh[(4*q+0)*AST + r]=vb.x; b_sh[(4*q+1)*AST + r]=vb.y;
        b_sh[(4*q+2)*AST + r]=vb.z; b_sh[(4*q+3)*AST + r]=vb.w;
      }
      __syncthreads();
      for(int c=0;c<CCH;c++){
        float4 A0 = *(const float4*)&a_sh[c*AST + tn*8];
        float4 A1 = *(const float4*)&a_sh[c*AST + tn*8 + 4];
        float4 B0 = *(const float4*)&b_sh[c*AST + tm*8];
        float4 B1 = *(const float4*)&b_sh[c*AST + tm*8 + 4];
        float af[8] = {A0.x,A0.y,A0.z,A0.w,A1.x,A1.y,A1.z,A1.w};
        float bf[8] = {B0.x,B0.y,B0.z,B0.w,B1.x,B1.y,B1.z,B1.w};
        #pragma unroll
        for(int i=0;i<8;i++){
          #pragma unroll
          for(int j=0;j<8;j++) acc[i][j] = fmaf(af[i], bf[j], acc[i][j]);
        }
      }
    }
    #pragma unroll
    for(int ph=0; ph<2; ph++){
      __syncthreads();                     // prev phase's selection reads done
      if(((tm>>3)&1) == ph){
        int tcol = (tm&7)*8;
        #pragma unroll
        for(int i=0;i<8;i++){
          *(float4*)&d_sh[(tn*8+i)*DST + tcol    ] = make_float4(acc[i][0],acc[i][1],acc[i][2],acc[i][3]);
          *(float4*)&d_sh[(tn*8+i)*DST + tcol + 4] = make_float4(acc[i][4],acc[i][5],acc[i][6],acc[i][7]);
        }
      }
      __syncthreads();
      const int mloc0 = ph*64 + sh*32;
      #pragma unroll
      for(int j4=0;j4<8;j4++){
        float4 dv = *(const float4*)&d_sh[sn*DST + sh*32 + 4*j4];
        int ml = mloc0 + 4*j4;
        float d0 = (2.f*dv.x - xxn_sel) - sxx[ml+0];
        float d1 = (2.f*dv.y - xxn_sel) - sxx[ml+1];
        float d2 = (2.f*dv.z - xxn_sel) - sxx[ml+2];
        float d3 = (2.f*dv.w - xxn_sel) - sxx[ml+3];
        float mx4 = fmaxf(fmaxf(d0,d1), fmaxf(d2,d3));
        if(mx4 > val[KK-1]){
          ins20(val,ind,d0, mtile+ml+0);
          ins20(val,ind,d1, mtile+ml+1);
          ins20(val,ind,d2, mtile+ml+2);
          ins20(val,ind,d3, mtile+ml+3);
        }
      }
    }
  }
  const int n = ntile + sn;
  const int l = blockIdx.z*2 + sh;     // 8 lists per n
  float*          pv = pval + (((size_t)(b*NN + n))*8 + l)*KK;
  unsigned short* pi = pidx + (((size_t)(b*NN + n))*8 + l)*KK;
  #pragma unroll
  for(int j=0;j<KK;j++){ pv[j]=val[j]; pi[j]=(unsigned short)ind[j]; }
}

__launch_bounds__(256) __global__ void knn_merge_k(const float* pval, const unsigned short* pidx, int* idx){
  int i = blockIdx.x*256 + threadIdx.x;   // BN
  const float* pv = pval + (size_t)i*MSPLIT*KK;
  const unsigned short* pi = pidx + (size_t)i*MSPLIT*KK;
  int* out = idx + (size_t)i*KK;
  float cv[MSPLIT]; int ci[MSPLIT]; int hp[MSPLIT];
  #pragma unroll
  for(int l=0;l<MSPLIT;l++){ cv[l]=pv[(size_t)l*KK]; ci[l]=pi[(size_t)l*KK]; hp[l]=1; }
  for(int j=0;j<KK;j++){
    float bv=-INFINITY; int bi=0x7fffffff; int bl=0;
    #pragma unroll
    for(int l=0;l<MSPLIT;l++){
      if (cv[l]>bv || (cv[l]==bv && ci[l]<bi)){ bv=cv[l]; bi=ci[l]; bl=l; }
    }
    out[j]=bi;
    if(hp[bl]<KK){ cv[bl]=pv[(size_t)bl*KK+hp[bl]]; ci[bl]=pi[(size_t)bl*KK+hp[bl]]; hp[bl]++; }
    else cv[bl]=-INFINITY;
  }
}

// ---------------- per-64-column qp + gather ----------------
template<int CIN>
__launch_bounds__(256) __global__ void qp64_k(const float* X, const float* W, int cb,
                                              float* q, float* bs){
  const int t   = blockIdx.x*256 + threadIdx.x;  // BN*8
  const int row = t >> 3;
  const int c0  = (t & 7) * 8;
  float xn[CIN];
  if constexpr (CIN % 4 == 0){
    #pragma unroll
    for(int c=0;c<CIN;c+=4){ float4 v = *(const float4*)(X + (size_t)row*CIN + c);
      xn[c]=v.x; xn[c+1]=v.y; xn[c+2]=v.z; xn[c+3]=v.w; }
  } else {
    #pragma unroll
    for(int c=0;c<CIN;c++) xn[c] = X[(size_t)row*CIN + c];
  }
  for(int oi=c0; oi<c0+8; oi++){
    const float* w = W + (size_t)(cb+oi)*2*CIN;
    float aq=0.f, ap=0.f;
    #pragma unroll
    for(int c=0;c<CIN;c++){ aq = fmaf(xn[c], w[c], aq); ap = fmaf(xn[c], w[CIN+c], ap); }
    q [(size_t)row*64 + oi] = aq;
    bs[(size_t)row*64 + oi] = ap - aq;
  }
}

template<int CFULL>
__launch_bounds__(256) __global__ void gather64_k(const float* q, const float* bs, const int* idx,
    const float* g, const float* bb, int cb, float* out){
  const int t  = blockIdx.x*256 + threadIdx.x;   // BN*64
  const int o  = t & 63;
  const int bn = t >> 6;
  const int b  = bn >> 11;
  const int* id = idx + (size_t)bn*KK;
  float base = bs[t];
  float mx = -INFINITY, mn = INFINITY;
  #pragma unroll
  for(int k=0;k<KK;k++){
    int ik = id[k];
    float v = q[((size_t)((b<<11) + ik))*64 + o];
    mx = fmaxf(mx, v); mn = fminf(mn, v);
  }
  float a  = g[cb+o] * RSQ;
  float bo = bb[cb+o];
  float h  = lrelu((a >= 0.f ? a*(mx+base) : a*(mn+base)) + bo);
  out[(size_t)bn*CFULL + cb + o] = h;
}

// ---------------- head: cat*W5^T with fused max/min over n ----------------
__launch_bounds__(256) __global__ void w5max_k(const float* x1,const float* x2,const float* x3,
    const float* x4, const float* W5T, unsigned* mxe, unsigned* mne){
  __shared__ float cat[16*512];
  __shared__ float redm[512], redn[512];
  const int blk = blockIdx.x;             // 1024 = B * (N/16)
  const int b  = blk >> 7;
  const int r0 = (blk & 127)*16;
  const int t  = threadIdx.x;
  const size_t bn0 = (size_t)b*NN + r0;
  for(int i=t; i<16*512; i+=256){
    int r = i>>9, c = i&511;
    size_t row = bn0 + r;
    float v;
    if(c<64)       v = x1[row*64  + c];
    else if(c<128) v = x2[row*64  + (c-64)];
    else if(c<256) v = x3[row*128 + (c-128)];
    else           v = x4[row*256 + (c-256)];
    cat[i] = v;
  }
  __syncthreads();
  const int half = t>>7, tq = t&127;
  const int rbase = half*8;
  float acc[4][8];
  #pragma unroll
  for(int j=0;j<4;j++){
    #pragma unroll
    for(int r=0;r<8;r++) acc[j][r]=0.f;
  }
  for(int c=0;c<512;c+=4){
    float w[4][4];
    #pragma unroll
    for(int cc=0;cc<4;cc++){
      #pragma unroll
      for(int j=0;j<4;j++) w[cc][j] = W5T[(size_t)(c+cc)*512 + tq + 128*j];
    }
    #pragma unroll
    for(int r=0;r<8;r++){
      float4 cv = *(const float4*)&cat[(rbase+r)*512 + c];
      #pragma unroll
      for(int j=0;j<4;j++)
        acc[j][r] = fmaf(cv.x, w[0][j], fmaf(cv.y, w[1][j], fmaf(cv.z, w[2][j], fmaf(cv.w, w[3][j], acc[j][r]))));
    }
  }
  float lmx[4], lmn[4];
  #pragma unroll
  for(int j=0;j<4;j++){
    float M=-INFINITY, m=INFINITY;
    #pragma unroll
    for(int r=0;r<8;r++){ M=fmaxf(M,acc[j][r]); m=fminf(m,acc[j][r]); }
    lmx[j]=M; lmn[j]=m;
  }
  if(half==0){
    #pragma unroll
    for(int j=0;j<4;j++){ redm[tq+128*j]=lmx[j]; redn[tq+128*j]=lmn[j]; }
  }
  __syncthreads();
  if(half==1){
    #pragma unroll
    for(int j=0;j<4;j++){
      int o = tq + 128*j;
      float M = fmaxf(lmx[j], redm[o]);
      float m = fminf(lmn[j], redn[o]);
      atomicMax(&mxe[b*512+o], encf(M));
      atomicMin(&mne[b*512+o], encf(m));
    }
  }
}

__launch_bounds__(256) __global__ void final_k(const unsigned* mxe, const unsigned* mne,
    const float* g5, const float* b5, const float* Wemb, float* out){
  const int b = blockIdx.x, t = threadIdx.x;
  __shared__ float h[512];
  for(int o=t; o<512; o+=256){
    float mx = decf(mxe[b*512+o]);
    float mn = decf(mne[b*512+o]);
    float a  = g5[o] * RSQ;
    float bo = b5[o];
    float hv = lrelu((a >= 0.f ? a*mx : a*mn) + bo);
    h[o] = hv;
    out[b*512+o] = hv;                       // feat (B,1,512)
  }
  __syncthreads();
  const float* wr = Wemb + (size_t)t*512;
  float s = 0.f;
  for(int o=0;o<512;o+=4){
    float4 w4 = *(const float4*)(wr+o);
    s = fmaf(h[o],w4.x, fmaf(h[o+1],w4.y, fmaf(h[o+2],w4.z, fmaf(h[o+3],w4.w, s))));
  }
  out[4096 + b*256 + t] = s;                 // embedding (B,256)
}

// ---------------- launch ----------------
extern "C" void kernel_launch(void* const* d_in, const int* in_sizes, int n_in,
                              void* d_out, int out_size, void* d_ws, size_t ws_size,
                              hipStream_t stream) {
  if (ws_size < WS_END * sizeof(float)) return;   // diagnostic guard

  const float* x0   = (const float*)d_in[0];
  const float* W1   = (const float*)d_in[1];
  const float* g1   = (const float*)d_in[2];
  const float* b1   = (const float*)d_in[3];
  const float* W2   = (const float*)d_in[4];
  const float* g2   = (const float*)d_in[5];
  const float* b2   = (const float*)d_in[6];
  const float* W3   = (const float*)d_in[7];
  const float* g3   = (const float*)d_in[8];
  const float* b3   = (const float*)d_in[9];
  const float* W4   = (const float*)d_in[10];
  const float* g4   = (const float*)d_in[11];
  const float* b4   = (const float*)d_in[12];
  const float* W5   = (const float*)d_in[13];
  const float* g5   = (const float*)d_in[14];
  const float* b5   = (const float*)d_in[15];
  const float* Wemb = (const float*)d_in[16];

  float* ws = (float*)d_ws;
  float* x1 = ws + OFF_X1;  float* x2 = ws + OFF_X2;
  float* x3 = ws + OFF_X3;  float* x4 = ws + OFF_X4;
  float* xx = ws + OFF_XX;
  // pv/pi alias into x4 (dead during all knn phases)
  float*          pv = ws + OFF_X4;
  unsigned short* pi = (unsigned short*)(ws + OFF_X4 + (size_t)BN*MSPLIT*KK);
  float* q  = ws + OFF_SC;
  float* bs = ws + OFF_SC + (size_t)BN*64;
  int*   id = (int*)(ws + OFF_ID);
  float* W5Tf = ws + OFF_W5T;
  unsigned* mxe = (unsigned*)(ws + OFF_MX);
  unsigned* mne = (unsigned*)(ws + OFF_MN);
  float* out = (float*)d_out;

  transposeW5_k<<<262144/256,256,0,stream>>>(W5, W5Tf);
  init_enc_k<<<BB*512/256,256,0,stream>>>(mxe, mne);

  dim3 ggrid(NN/128, BB, 4);

  // layer 1 (3 -> 64)
  sqnorm_k<3><<<BN/256,256,0,stream>>>(x0, xx);
  knn_part2_k<3,256><<<dim3(NN/256,BB,MSPLIT),256,0,stream>>>(x0, xx, pv, pi);
  knn_merge_k<<<BN/256,256,0,stream>>>(pv, pi, id);
  qp64_k<3><<<BN*8/256,256,0,stream>>>(x0, W1, 0, q, bs);
  gather64_k<64><<<BN*64/256,256,0,stream>>>(q, bs, id, g1, b1, 0, x1);

  // layer 2 (64 -> 64)
  sqnorm_k<64><<<BN/256,256,0,stream>>>(x1, xx);
  knn_gemm_k<64><<<ggrid,256,0,stream>>>(x1, xx, pv, pi);
  knn_merge_k<<<BN/256,256,0,stream>>>(pv, pi, id);
  qp64_k<64><<<BN*8/256,256,0,stream>>>(x1, W2, 0, q, bs);
  gather64_k<64><<<BN*64/256,256,0,stream>>>(q, bs, id, g2, b2, 0, x2);

  // layer 3 (64 -> 128)
  sqnorm_k<64><<<BN/256,256,0,stream>>>(x2, xx);
  knn_gemm_k<64><<<ggrid,256,0,stream>>>(x2, xx, pv, pi);
  knn_merge_k<<<BN/256,256,0,stream>>>(pv, pi, id);
  for(int cb=0; cb<128; cb+=64){
    qp64_k<64><<<BN*8/256,256,0,stream>>>(x2, W3, cb, q, bs);
    gather64_k<128><<<BN*64/256,256,0,stream>>>(q, bs, id, g3, b3, cb, x3);
  }

  // layer 4 (128 -> 256)
  sqnorm_k<128><<<BN/256,256,0,stream>>>(x3, xx);
  knn_gemm_k<128><<<ggrid,256,0,stream>>>(x3, xx, pv, pi);
  knn_merge_k<<<BN/256,256,0,stream>>>(pv, pi, id);
  for(int cb=0; cb<256; cb+=64){
    qp64_k<128><<<BN*8/256,256,0,stream>>>(x3, W4, cb, q, bs);
    gather64_k<256><<<BN*64/256,256,0,stream>>>(q, bs, id, g4, b4, cb, x4);
  }

  // head
  w5max_k<<<BB*(NN/16),256,0,stream>>>(x1, x2, x3, x4, W5Tf, mxe, mne);
  final_k<<<BB,256,0,stream>>>(mxe, mne, g5, b5, Wemb, out);
}

// Round 8
// 5707.561 us; speedup vs baseline: 1.5561x; 1.5561x over previous
//
#include <hip/hip_runtime.h>
#include <hip/hip_bf16.h>

#define BB 8
#define NN 2048
#define KK 20
#define BN (BB*NN)
#define MSPLIT 8   // partial lists per n (gemm path: 4 z-chunks x 2 halves)
#define RSQ 0.99999500003749969f   // 1/sqrt(1+1e-5)

// ---------------- workspace layout (float-slot units), 44.3 MiB total ----------------
constexpr size_t OFF_X1  = 0;                          // BN*64
constexpr size_t OFF_X2  = OFF_X1  + (size_t)BN*64;    // BN*64
constexpr size_t OFF_X3  = OFF_X2  + (size_t)BN*64;    // BN*128
constexpr size_t OFF_X4  = OFF_X3  + (size_t)BN*128;   // BN*256 (pv/pi alias here during knn)
constexpr size_t OFF_XX  = OFF_X4  + (size_t)BN*256;   // BN
constexpr size_t OFF_SC  = OFF_XX  + BN;               // scratch: q,bs (BN*128 of BN*160)
constexpr size_t OFF_ID  = OFF_SC  + (size_t)BN*160;   // int BN*20
constexpr size_t OFF_W5T = OFF_ID  + (size_t)BN*20;    // 512*512, [c][o]
constexpr size_t OFF_MX  = OFF_W5T + 512*512;          // uint B*512
constexpr size_t OFF_MN  = OFF_MX  + BB*512;
constexpr size_t WS_END  = OFF_MN  + BB*512;           // 11,624,448 floats

__device__ inline unsigned encf(float f){ unsigned u=__float_as_uint(f); return (u&0x80000000u)? ~u : (u|0x80000000u); }
__device__ inline float decf(unsigned e){ unsigned u=(e&0x80000000u)? (e&0x7fffffffu) : ~e; return __uint_as_float(u); }
__device__ inline float lrelu(float h){ return h>=0.f ? h : 0.2f*h; }

__device__ inline void ins20(float (&val)[KK], int (&ind)[KK], float cv, int ci){
  if (cv > val[KK-1]){
    #pragma unroll
    for(int j=0;j<KK;j++){
      if (cv > val[j]){ float tv=val[j]; int ti=ind[j]; val[j]=cv; ind[j]=ci; cv=tv; ci=ti; }
    }
  }
}

// ---------------- init ----------------
__global__ void transposeW5_k(const float* s, float* d){
  int i = blockIdx.x*256 + threadIdx.x;   // 262144
  int o = i>>9, c = i&511;
  d[c*512+o] = s[i];
}
__global__ void init_enc_k(unsigned* mx, unsigned* mn){
  int i = blockIdx.x*256 + threadIdx.x;   // 4096
  mx[i] = 0x007FFFFFu;   // enc(-inf)
  mn[i] = 0xFF800000u;   // enc(+inf)
}

// ---------------- KNN ----------------
template<int C>
__launch_bounds__(256) __global__ void sqnorm_k(const float* X, float* xx){
  int i = blockIdx.x*256 + threadIdx.x;   // BN
  const float* r = X + (size_t)i*C;
  float s = 0.f;
  #pragma unroll
  for(int c=0;c<C;c++) s = fmaf(r[c], r[c], s);
  xx[i] = s;
}

// per-n kernel kept only for C=3
template<int C, int MC>
__launch_bounds__(256) __global__ void knn_part2_k(const float* __restrict__ X, const float* __restrict__ xx,
                                                   float* __restrict__ pval, unsigned short* __restrict__ pidx){
  __shared__ float sm[MC*C];
  __shared__ float sxx[MC];
  const int b   = blockIdx.y;
  const int tid = threadIdx.x;
  const int n   = blockIdx.x*256 + tid;
  const float* Xb = X + (size_t)b*NN*C;
  float xn[C];
  #pragma unroll
  for(int c=0;c<C;c++) xn[c] = Xb[(size_t)n*C + c];
  const float xxn = xx[b*NN+n];
  const float* xxb = xx + b*NN;
  float val[KK]; int ind[KK];
  #pragma unroll
  for(int j=0;j<KK;j++){ val[j]=-INFINITY; ind[j]=0; }

  const int m0 = blockIdx.z*(NN/MSPLIT);
  for(int ms=m0; ms<m0+NN/MSPLIT; ms+=MC){
    __syncthreads();
    for(int i=tid; i<MC*C; i+=256) sm[i] = Xb[(size_t)ms*C + i];
    for(int i=tid; i<MC; i+=256) sxx[i] = xxb[ms+i];
    __syncthreads();
    for(int mg=0; mg<MC; mg+=4){
      float a0=0.f, a1=0.f, a2=0.f, a3=0.f;
      #pragma unroll
      for(int c=0;c<C;c++){
        float xc = xn[c];
        a0=fmaf(xc, sm[(size_t)(mg+0)*C+c], a0);
        a1=fmaf(xc, sm[(size_t)(mg+1)*C+c], a1);
        a2=fmaf(xc, sm[(size_t)(mg+2)*C+c], a2);
        a3=fmaf(xc, sm[(size_t)(mg+3)*C+c], a3);
      }
      float d0 = (2.f*a0 - xxn) - sxx[mg+0];
      float d1 = (2.f*a1 - xxn) - sxx[mg+1];
      float d2 = (2.f*a2 - xxn) - sxx[mg+2];
      float d3 = (2.f*a3 - xxn) - sxx[mg+3];
      float mx4 = fmaxf(fmaxf(d0,d1), fmaxf(d2,d3));
      if (mx4 > val[KK-1]){
        ins20(val, ind, d0, ms+mg+0);
        ins20(val, ind, d1, ms+mg+1);
        ins20(val, ind, d2, ms+mg+2);
        ins20(val, ind, d3, ms+mg+3);
      }
    }
  }
  float*          pv = pval + (((size_t)(b*NN+n))*MSPLIT + blockIdx.z)*KK;
  unsigned short* pi = pidx + (((size_t)(b*NN+n))*MSPLIT + blockIdx.z)*KK;
  #pragma unroll
  for(int j=0;j<KK;j++){ pv[j]=val[j]; pi[j]=(unsigned short)ind[j]; }
}

#define FMA_ROW(I) \
  acc[I][0]=fmaf(a,b0,acc[I][0]); acc[I][1]=fmaf(a,b1,acc[I][1]); \
  acc[I][2]=fmaf(a,b2,acc[I][2]); acc[I][3]=fmaf(a,b3,acc[I][3]); \
  acc[I][4]=fmaf(a,b4,acc[I][4]); acc[I][5]=fmaf(a,b5,acc[I][5]); \
  acc[I][6]=fmaf(a,b6,acc[I][6]); acc[I][7]=fmaf(a,b7,acc[I][7]);

// GEMM-tiled KNN: block = 128n x 128m, thread = 8x8 micro-tile.
// d_sh round-trip uses scalar b32 (selection reads conflict-free at stride 65).
// amdgpu_waves_per_eu(2,2): pin VGPR budget at 256 -> no spill (R7 lesson).
template<int C>
__attribute__((amdgpu_waves_per_eu(2,2)))
__launch_bounds__(256) __global__ void knn_gemm_k(const float* __restrict__ X, const float* __restrict__ xx,
                                                  float* __restrict__ pval, unsigned short* __restrict__ pidx){
  constexpr int AST = 132;
  constexpr int DST = 65;
  __shared__ __align__(16) float a_sh[16*AST];
  __shared__ __align__(16) float b_sh[16*AST];
  __shared__ float d_sh[128*DST];
  __shared__ float sxx[128];

  const int tid = threadIdx.x;
  const int b   = blockIdx.y;
  const int ntile = blockIdx.x*128;
  const int mbase = blockIdx.z*(NN/4);
  const int tm = (tid&7) | ((tid>>4)&8);   // bit7 -> tm bit3 (phase)
  const int tn = (tid>>3)&15;
  const int myph = tm >> 3;
  const int tm7 = tm & 7;
  const int sn = tid >> 1, sh = tid & 1;

  const float* Xb  = X  + (size_t)b*NN*C;
  const float* xxb = xx + (size_t)b*NN;
  const float xxn_sel = xxb[ntile + sn];

  float val[KK]; int ind[KK];
  #pragma unroll
  for(int j=0;j<KK;j++){ val[j]=-INFINITY; ind[j]=0; }

  for(int mt=0; mt<4; ++mt){
    const int mtile = mbase + mt*128;
    __syncthreads();                       // prev tile's selection done (sxx/d_sh free)
    if(tid < 128) sxx[tid] = xxb[mtile + tid];
    float acc[8][8];
    #pragma unroll
    for(int i=0;i<8;i++){
      #pragma unroll
      for(int j=0;j<8;j++) acc[i][j]=0.f;
    }
    for(int cc=0; cc<C; cc+=16){
      __syncthreads();                     // prev chunk's frag reads done
      #pragma unroll
      for(int s=0;s<2;s++){
        int i = tid + 256*s; int r = i>>2, q = i&3;
        float4 va = *(const float4*)&Xb[(size_t)(ntile + r)*C + cc + 4*q];
        a_sh[(4*q+0)*AST + r]=va.x; a_sh[(4*q+1)*AST + r]=va.y;
        a_sh[(4*q+2)*AST + r]=va.z; a_sh[(4*q+3)*AST + r]=va.w;
        float4 vb = *(const float4*)&Xb[(size_t)(mtile + r)*C + cc + 4*q];
        b_sh[(4*q+0)*AST + r]=vb.x; b_sh[(4*q+1)*AST + r]=vb.y;
        b_sh[(4*q+2)*AST + r]=vb.z; b_sh[(4*q+3)*AST + r]=vb.w;
      }
      __syncthreads();
      #pragma unroll
      for(int c=0;c<16;c++){
        float4 A0 = *(const float4*)&a_sh[c*AST + tn*8];
        float4 A1 = *(const float4*)&a_sh[c*AST + tn*8 + 4];
        float4 B0 = *(const float4*)&b_sh[c*AST + tm*8];
        float4 B1 = *(const float4*)&b_sh[c*AST + tm*8 + 4];
        float b0=B0.x,b1=B0.y,b2=B0.z,b3=B0.w,b4=B1.x,b5=B1.y,b6=B1.z,b7=B1.w;
        float a;
        a=A0.x; FMA_ROW(0)
        a=A0.y; FMA_ROW(1)
        a=A0.z; FMA_ROW(2)
        a=A0.w; FMA_ROW(3)
        a=A1.x; FMA_ROW(4)
        a=A1.y; FMA_ROW(5)
        a=A1.z; FMA_ROW(6)
        a=A1.w; FMA_ROW(7)
      }
    }
    #pragma unroll
    for(int ph=0; ph<2; ph++){
      __syncthreads();                     // prev phase's selection reads done
      if(myph == ph){
        #pragma unroll
        for(int i=0;i<8;i++){
          #pragma unroll
          for(int j=0;j<8;j++)
            d_sh[(size_t)(tn*8+i)*DST + tm7*8 + j] = acc[i][j];
        }
      }
      __syncthreads();
      #pragma unroll
      for(int j4=0;j4<8;j4++){
        int mj = sh*32 + 4*j4;
        float v0 = d_sh[(size_t)sn*DST + mj+0];
        float v1 = d_sh[(size_t)sn*DST + mj+1];
        float v2 = d_sh[(size_t)sn*DST + mj+2];
        float v3 = d_sh[(size_t)sn*DST + mj+3];
        int ml = ph*64 + mj;
        float d0 = (2.f*v0 - xxn_sel) - sxx[ml+0];
        float d1 = (2.f*v1 - xxn_sel) - sxx[ml+1];
        float d2 = (2.f*v2 - xxn_sel) - sxx[ml+2];
        float d3 = (2.f*v3 - xxn_sel) - sxx[ml+3];
        float mx4 = fmaxf(fmaxf(d0,d1), fmaxf(d2,d3));
        if(mx4 > val[KK-1]){
          ins20(val,ind,d0, mtile+ml+0);
          ins20(val,ind,d1, mtile+ml+1);
          ins20(val,ind,d2, mtile+ml+2);
          ins20(val,ind,d3, mtile+ml+3);
        }
      }
    }
  }
  const int n = ntile + sn;
  const int l = blockIdx.z*2 + sh;     // 8 lists per n
  float*          pv = pval + (((size_t)(b*NN + n))*8 + l)*KK;
  unsigned short* pi = pidx + (((size_t)(b*NN + n))*8 + l)*KK;
  #pragma unroll
  for(int j=0;j<KK;j++){ pv[j]=val[j]; pi[j]=(unsigned short)ind[j]; }
}

__launch_bounds__(256) __global__ void knn_merge_k(const float* pval, const unsigned short* pidx, int* idx){
  int i = blockIdx.x*256 + threadIdx.x;   // BN
  const float* pv = pval + (size_t)i*MSPLIT*KK;
  const unsigned short* pi = pidx + (size_t)i*MSPLIT*KK;
  int* out = idx + (size_t)i*KK;
  float cv[MSPLIT]; int ci[MSPLIT]; int hp[MSPLIT];
  #pragma unroll
  for(int l=0;l<MSPLIT;l++){ cv[l]=pv[(size_t)l*KK]; ci[l]=pi[(size_t)l*KK]; hp[l]=1; }
  for(int j=0;j<KK;j++){
    float bv=-INFINITY; int bi=0x7fffffff; int bl=0;
    #pragma unroll
    for(int l=0;l<MSPLIT;l++){
      if (cv[l]>bv || (cv[l]==bv && ci[l]<bi)){ bv=cv[l]; bi=ci[l]; bl=l; }
    }
    out[j]=bi;
    if(hp[bl]<KK){ cv[bl]=pv[(size_t)bl*KK+hp[bl]]; ci[bl]=pi[(size_t)bl*KK+hp[bl]]; hp[bl]++; }
    else cv[bl]=-INFINITY;
  }
}

// ---------------- per-64-column qp + gather ----------------
template<int CIN>
__launch_bounds__(256) __global__ void qp64_k(const float* X, const float* W, int cb,
                                              float* q, float* bs){
  const int t   = blockIdx.x*256 + threadIdx.x;  // BN*8
  const int row = t >> 3;
  const int c0  = (t & 7) * 8;
  float xn[CIN];
  if constexpr (CIN % 4 == 0){
    #pragma unroll
    for(int c=0;c<CIN;c+=4){ float4 v = *(const float4*)(X + (size_t)row*CIN + c);
      xn[c]=v.x; xn[c+1]=v.y; xn[c+2]=v.z; xn[c+3]=v.w; }
  } else {
    #pragma unroll
    for(int c=0;c<CIN;c++) xn[c] = X[(size_t)row*CIN + c];
  }
  for(int oi=c0; oi<c0+8; oi++){
    const float* w = W + (size_t)(cb+oi)*2*CIN;
    float aq=0.f, ap=0.f;
    #pragma unroll
    for(int c=0;c<CIN;c++){ aq = fmaf(xn[c], w[c], aq); ap = fmaf(xn[c], w[CIN+c], ap); }
    q [(size_t)row*64 + oi] = aq;
    bs[(size_t)row*64 + oi] = ap - aq;
  }
}

template<int CFULL>
__launch_bounds__(256) __global__ void gather64_k(const float* q, const float* bs, const int* idx,
    const float* g, const float* bb, int cb, float* out){
  const int t  = blockIdx.x*256 + threadIdx.x;   // BN*64
  const int o  = t & 63;
  const int bn = t >> 6;
  const int b  = bn >> 11;
  const int* id = idx + (size_t)bn*KK;
  float base = bs[t];
  float mx = -INFINITY, mn = INFINITY;
  #pragma unroll
  for(int k=0;k<KK;k++){
    int ik = id[k];
    float v = q[((size_t)((b<<11) + ik))*64 + o];
    mx = fmaxf(mx, v); mn = fminf(mn, v);
  }
  float a  = g[cb+o] * RSQ;
  float bo = bb[cb+o];
  float h  = lrelu((a >= 0.f ? a*(mx+base) : a*(mn+base)) + bo);
  out[(size_t)bn*CFULL + cb + o] = h;
}

// ---------------- head: cat*W5^T with fused max/min over n ----------------
__launch_bounds__(256) __global__ void w5max_k(const float* x1,const float* x2,const float* x3,
    const float* x4, const float* W5T, unsigned* mxe, unsigned* mne){
  __shared__ float cat[16*512];
  __shared__ float redm[512], redn[512];
  const int blk = blockIdx.x;             // 1024 = B * (N/16)
  const int b  = blk >> 7;
  const int r0 = (blk & 127)*16;
  const int t  = threadIdx.x;
  const size_t bn0 = (size_t)b*NN + r0;
  for(int i=t; i<16*512; i+=256){
    int r = i>>9, c = i&511;
    size_t row = bn0 + r;
    float v;
    if(c<64)       v = x1[row*64  + c];
    else if(c<128) v = x2[row*64  + (c-64)];
    else if(c<256) v = x3[row*128 + (c-128)];
    else           v = x4[row*256 + (c-256)];
    cat[i] = v;
  }
  __syncthreads();
  const int half = t>>7, tq = t&127;
  const int rbase = half*8;
  float acc[4][8];
  #pragma unroll
  for(int j=0;j<4;j++){
    #pragma unroll
    for(int r=0;r<8;r++) acc[j][r]=0.f;
  }
  for(int c=0;c<512;c+=4){
    float w[4][4];
    #pragma unroll
    for(int cc=0;cc<4;cc++){
      #pragma unroll
      for(int j=0;j<4;j++) w[cc][j] = W5T[(size_t)(c+cc)*512 + tq + 128*j];
    }
    #pragma unroll
    for(int r=0;r<8;r++){
      float4 cv = *(const float4*)&cat[(rbase+r)*512 + c];
      #pragma unroll
      for(int j=0;j<4;j++)
        acc[j][r] = fmaf(cv.x, w[0][j], fmaf(cv.y, w[1][j], fmaf(cv.z, w[2][j], fmaf(cv.w, w[3][j], acc[j][r]))));
    }
  }
  float lmx[4], lmn[4];
  #pragma unroll
  for(int j=0;j<4;j++){
    float M=-INFINITY, m=INFINITY;
    #pragma unroll
    for(int r=0;r<8;r++){ M=fmaxf(M,acc[j][r]); m=fminf(m,acc[j][r]); }
    lmx[j]=M; lmn[j]=m;
  }
  if(half==0){
    #pragma unroll
    for(int j=0;j<4;j++){ redm[tq+128*j]=lmx[j]; redn[tq+128*j]=lmn[j]; }
  }
  __syncthreads();
  if(half==1){
    #pragma unroll
    for(int j=0;j<4;j++){
      int o = tq + 128*j;
      float M = fmaxf(lmx[j], redm[o]);
      float m = fminf(lmn[j], redn[o]);
      atomicMax(&mxe[b*512+o], encf(M));
      atomicMin(&mne[b*512+o], encf(m));
    }
  }
}

__launch_bounds__(256) __global__ void final_k(const unsigned* mxe, const unsigned* mne,
    const float* g5, const float* b5, const float* Wemb, float* out){
  const int b = blockIdx.x, t = threadIdx.x;
  __shared__ float h[512];
  for(int o=t; o<512; o+=256){
    float mx = decf(mxe[b*512+o]);
    float mn = decf(mne[b*512+o]);
    float a  = g5[o] * RSQ;
    float bo = b5[o];
    float hv = lrelu((a >= 0.f ? a*mx : a*mn) + bo);
    h[o] = hv;
    out[b*512+o] = hv;                       // feat (B,1,512)
  }
  __syncthreads();
  const float* wr = Wemb + (size_t)t*512;
  float s = 0.f;
  for(int o=0;o<512;o+=4){
    float4 w4 = *(const float4*)(wr+o);
    s = fmaf(h[o],w4.x, fmaf(h[o+1],w4.y, fmaf(h[o+2],w4.z, fmaf(h[o+3],w4.w, s))));
  }
  out[4096 + b*256 + t] = s;                 // embedding (B,256)
}

// ---------------- launch ----------------
extern "C" void kernel_launch(void* const* d_in, const int* in_sizes, int n_in,
                              void* d_out, int out_size, void* d_ws, size_t ws_size,
                              hipStream_t stream) {
  if (ws_size < WS_END * sizeof(float)) return;   // diagnostic guard

  const float* x0   = (const float*)d_in[0];
  const float* W1   = (const float*)d_in[1];
  const float* g1   = (const float*)d_in[2];
  const float* b1   = (const float*)d_in[3];
  const float* W2   = (const float*)d_in[4];
  const float* g2   = (const float*)d_in[5];
  const float* b2   = (const float*)d_in[6];
  const float* W3   = (const float*)d_in[7];
  const float* g3   = (const float*)d_in[8];
  const float* b3   = (const float*)d_in[9];
  const float* W4   = (const float*)d_in[10];
  const float* g4   = (const float*)d_in[11];
  const float* b4   = (const float*)d_in[12];
  const float* W5   = (const float*)d_in[13];
  const float* g5   = (const float*)d_in[14];
  const float* b5   = (const float*)d_in[15];
  const float* Wemb = (const float*)d_in[16];

  float* ws = (float*)d_ws;
  float* x1 = ws + OFF_X1;  float* x2 = ws + OFF_X2;
  float* x3 = ws + OFF_X3;  float* x4 = ws + OFF_X4;
  float* xx = ws + OFF_XX;
  // pv/pi alias into x4 (dead during all knn phases)
  float*          pv = ws + OFF_X4;
  unsigned short* pi = (unsigned short*)(ws + OFF_X4 + (size_t)BN*MSPLIT*KK);
  float* q  = ws + OFF_SC;
  float* bs = ws + OFF_SC + (size_t)BN*64;
  int*   id = (int*)(ws + OFF_ID);
  float* W5Tf = ws + OFF_W5T;
  unsigned* mxe = (unsigned*)(ws + OFF_MX);
  unsigned* mne = (unsigned*)(ws + OFF_MN);
  float* out = (float*)d_out;

  transposeW5_k<<<262144/256,256,0,stream>>>(W5, W5Tf);
  init_enc_k<<<BB*512/256,256,0,stream>>>(mxe, mne);

  dim3 ggrid(NN/128, BB, 4);

  // layer 1 (3 -> 64)
  sqnorm_k<3><<<BN/256,256,0,stream>>>(x0, xx);
  knn_part2_k<3,256><<<dim3(NN/256,BB,MSPLIT),256,0,stream>>>(x0, xx, pv, pi);
  knn_merge_k<<<BN/256,256,0,stream>>>(pv, pi, id);
  qp64_k<3><<<BN*8/256,256,0,stream>>>(x0, W1, 0, q, bs);
  gather64_k<64><<<BN*64/256,256,0,stream>>>(q, bs, id, g1, b1, 0, x1);

  // layer 2 (64 -> 64)
  sqnorm_k<64><<<BN/256,256,0,stream>>>(x1, xx);
  knn_gemm_k<64><<<ggrid,256,0,stream>>>(x1, xx, pv, pi);
  knn_merge_k<<<BN/256,256,0,stream>>>(pv, pi, id);
  qp64_k<64><<<BN*8/256,256,0,stream>>>(x1, W2, 0, q, bs);
  gather64_k<64><<<BN*64/256,256,0,stream>>>(q, bs, id, g2, b2, 0, x2);

  // layer 3 (64 -> 128)
  sqnorm_k<64><<<BN/256,256,0,stream>>>(x2, xx);
  knn_gemm_k<64><<<ggrid,256,0,stream>>>(x2, xx, pv, pi);
  knn_merge_k<<<BN/256,256,0,stream>>>(pv, pi, id);
  for(int cb=0; cb<128; cb+=64){
    qp64_k<64><<<BN*8/256,256,0,stream>>>(x2, W3, cb, q, bs);
    gather64_k<128><<<BN*64/256,256,0,stream>>>(q, bs, id, g3, b3, cb, x3);
  }

  // layer 4 (128 -> 256)
  sqnorm_k<128><<<BN/256,256,0,stream>>>(x3, xx);
  knn_gemm_k<128><<<ggrid,256,0,stream>>>(x3, xx, pv, pi);
  knn_merge_k<<<BN/256,256,0,stream>>>(pv, pi, id);
  for(int cb=0; cb<256; cb+=64){
    qp64_k<128><<<BN*8/256,256,0,stream>>>(x3, W4, cb, q, bs);
    gather64_k<256><<<BN*64/256,256,0,stream>>>(q, bs, id, g4, b4, cb, x4);
  }

  // head
  w5max_k<<<BB*(NN/16),256,0,stream>>>(x1, x2, x3, x4, W5Tf, mxe, mne);
  final_k<<<BB,256,0,stream>>>(mxe, mne, g5, b5, Wemb, out);
}